// Round 15
// baseline (247.585 us; speedup 1.0000x reference)
//
#include <hip/hip_runtime.h>
#include <math.h>

// ---------------------------------------------------------------------------
// Raw-outer-product aggregation, K=992. No Z records at all:
//   G'[n][t][u] = Sum_{e->n} yprod_t(Y_e) * f_u(src_e),  t in [0,31):
//     t0      = Y0*s
//     t1+jy   = Y1[jy]*s
//     t4+i    = Y0*v[i]
//     t7+jy*3+i  = Y1[jy]*v[i]
//     t16+jy*3+i = Y2[jy]*v[i]
//   out[n][j] = Sum_k G'[n][k] * WBT[j][k]   (16x16x32 bf16 MFMA, 31 K-steps)
// All CG/alpha coefficients folded into WBT (linear paths).
// Workspace (4B words):
//   cg      [0..128)     CG tensors (alpha/norm folded)
//   cursor  [128 .. +N)  memset0 -> hist -> prefix -> cursor -> row ends
//   eorder  [.. +E)      edge ids sorted by dst
//   fb      [.. +64N)    feat bf16 [N][32] uint2 {P(s,vx),P(vy,vz)}
//   WBT     [.. +63488)  ushort [128][992]  (cg x W folded, bf16)
//   tilesums[.. +256)    (FIXED: was overlapping WBT's 2nd half in R14 ->
//                         race -> garbage cursor -> OOB reads -> abort)
// ---------------------------------------------------------------------------

typedef __attribute__((ext_vector_type(8))) short bf16x8;
typedef __attribute__((ext_vector_type(4))) float f32x4;

__device__ inline float blo(unsigned u) { return __uint_as_float(u << 16); }
__device__ inline float bhi(unsigned u) { return __uint_as_float(u & 0xffff0000u); }
__device__ inline unsigned bpack(float a, float b) {
    unsigned ua = __float_as_uint(a);
    ua = (ua + 0x7fffu + ((ua >> 16) & 1u)) >> 16;
    unsigned ub = __float_as_uint(b);
    ub = (ub + 0x7fffu + ((ub >> 16) & 1u)) & 0xffff0000u;
    return ua | ub;
}
__device__ inline unsigned short bh(float a) {
    unsigned ua = __float_as_uint(a);
    return (unsigned short)((ua + 0x7fffu + ((ua >> 16) & 1u)) >> 16);
}

// f32 factorial (all n <= 7 here; exact in f32). Register-only scalar loop.
__device__ inline float dfactf(int n) {
    float r = 1.0f;
    for (int i = 2; i <= n; ++i) r *= (float)i;
    return r;
}

// SU(2) "CG" element via the reference's exact Racah-form (all six m-dependent
// factorials in the NUMERATOR — non-standard but matches the reference).
__device__ float su2_cg_elem_f(int l1, int l2, int l3, int i, int k, int n) {
    int m1 = i - l1, m2 = k - l2, m3 = n - l3;
    if (m1 + m2 != m3) return 0.0f;
    int vmin = -l1 + l2 + m3;
    if (-l1 + m1 > vmin) vmin = -l1 + m1;
    if (0 > vmin) vmin = 0;
    int vmax = l2 + l3 + m1;
    if (l3 - l1 + l2 < vmax) vmax = l3 - l1 + l2;
    if (l3 + m3 < vmax) vmax = l3 + m3;
    if (vmax < vmin) return 0.0f;
    float c = sqrtf((float)(2 * l3 + 1) * dfactf(l3 + l1 - l2) *
                    dfactf(l3 - l1 + l2) * dfactf(l1 + l2 - l3) /
                    dfactf(l1 + l2 + l3 + 1));
    c *= sqrtf(dfactf(l3 + m3) * dfactf(l3 - m3) * dfactf(l1 - m1) *
               dfactf(l1 + m1) * dfactf(l2 - m2) * dfactf(l2 + m2));
    float s = 0.0f;
    for (int v = vmin; v <= vmax; ++v) {
        float term = dfactf(l2 + l3 + m1 - v) * dfactf(l1 - m1 + v) /
                     (dfactf(v) * dfactf(l3 - l1 + l2 - v) *
                      dfactf(l3 + m3 - v) * dfactf(v + l1 - l2 - m3));
        if ((v + l2 + m2) & 1) term = -term;
        s += term;
    }
    return c * s;
}

// cg compute by one 256-thread block. All dynamically-indexed arrays in LDS
// (runtime-indexed private arrays go to SCRATCH -> 110us straggler, rule #20).
__device__ void cg_compute_block(float* __restrict__ cg_out) {
    __shared__ float sqr[3][5][5], sqi[3][5][5];  // q matrices for l=0,1,2
    __shared__ float vals[5][45];
    int t = threadIdx.x;
    if (t < 75) {
        int l = t / 25, a = (t % 25) / 5, b = t % 5;
        float re = 0.f, im = 0.f;
        const float inv = 0.70710678118654752440f;
        int m = a - l;
        if (a < 5 && b < 5) {
            if (m < 0) {
                if (b == l - m) re = inv;        // col l+|m|
                if (b == l + m) im = -inv;       // col l-|m|
            } else if (m == 0) {
                if (b == l && a == l) re = 1.f;
            } else {
                float sgn = (m & 1) ? -1.f : 1.f;
                if (b == l + m) re = sgn * inv;
                if (b == l - m) im = sgn * inv;
            }
        }
        if (l == 1) { float r = re; re = im; im = -r; }      // * (-i)
        else if (l == 2) { re = -re; im = -im; }             // * (-1)
        sqr[l][a][b] = re;
        sqi[l][a][b] = im;
    }
    __syncthreads();
    const int l1s[5] = {0, 0, 1, 1, 1};
    const int l2s[5] = {0, 1, 0, 1, 2};
    const int l3s[5] = {0, 1, 1, 0, 1};
    const int offs[5] = {0, 1, 10, 19, 28};
    const float alphas[5] = {0.125f, 0.10206207261596575f, 0.10206207261596575f,
                             0.125f, 0.10206207261596575f};
    int p = t / 45, idx = t % 45;
    bool active = (t < 225);
    float acc = 0.0f;
    int d1 = 0, d2 = 0, d3 = 0;
    if (active) {
        int l1 = l1s[p], l2 = l2s[p], l3 = l3s[p];
        d1 = 2 * l1 + 1; d2 = 2 * l2 + 1; d3 = 2 * l3 + 1;
        if (idx < d1 * d2 * d3) {
            int j = idx / (d2 * d3);
            int rem = idx % (d2 * d3);
            int l_ = rem / d3, m = rem % d3;
            for (int i = 0; i < d1; ++i)
                for (int k = 0; k < d2; ++k)
                    for (int n = 0; n < d3; ++n) {
                        float C = su2_cg_elem_f(l1, l2, l3, i, k, n);
                        if (C == 0.0f) continue;
                        float ar = sqr[l1][i][j], ai = sqi[l1][i][j];
                        float br = sqr[l2][k][l_], bi = sqi[l2][k][l_];
                        float cr = sqr[l3][n][m], ci = sqi[l3][n][m];
                        float abr = ar * br - ai * bi;
                        float abi = ar * bi + ai * br;
                        acc += (abr * cr + abi * ci) * C;  // Re(a*b*conj(c))
                    }
        }
        vals[p][idx] = acc;
    }
    __syncthreads();
    if (active && idx < d1 * d2 * d3) {
        float n2 = 0.0f;
        for (int q = 0; q < 45; ++q) n2 += vals[p][q] * vals[p][q];
        cg_out[offs[p] + idx] = acc * alphas[p] / sqrtf(n2);
    }
}

// ---------------------------------------------------------------------------
// prep: cg (block 0, LDS-based) + feat->bf16 transcode + dst histogram
// ---------------------------------------------------------------------------
__global__ __launch_bounds__(256) void prep_kernel(
    const float* __restrict__ feat, const int* __restrict__ eidx,
    int* __restrict__ cursor, unsigned* __restrict__ fb,
    float* __restrict__ cg, int N, int E) {
    if (blockIdx.x == 0) cg_compute_block(cg);
    int t = blockIdx.x * 256 + threadIdx.x;
    if (t < N * 32) {
        int n = t >> 5, u = t & 31;
        const float* f = feat + (size_t)n * 128;
        float s = f[u];
        float vx = f[32 + 3 * u], vy = f[33 + 3 * u], vz = f[34 + 3 * u];
        ((uint2*)fb)[t] = make_uint2(bpack(s, vx), bpack(vy, vz));
    }
    if (t < E) atomicAdd(&cursor[eidx[E + t]], 1);
}

// ---------------------------------------------------------------------------
// scanA (fused with WBT build, grid-strided over 128*992 entries).
// WBT[j][k], k = t*32+u:
//   j<32:  t0 -> cg0*W0[u][j] ; t=7+jy*3+i -> cg3[i][jy]*W3[u][j]
//   j>=32 (w=(j-32)/3, m=(j-32)%3):
//     t=1+jy -> cg1[jy][m]*W1[u][w] ; t=4+i -> cg2[i][m]*W2[u][w]
//     t=16+jy*3+i -> cg4[i][jy][m]*W4[u][w]
// ---------------------------------------------------------------------------
__global__ __launch_bounds__(256) void scanA_kernel(
    const int* __restrict__ counts, int* __restrict__ tilesums, int N,
    const float* __restrict__ W, const float* __restrict__ cg,
    unsigned short* __restrict__ WBT, int nthreads) {
    __shared__ int lds[4];
    int i = blockIdx.x * 256 + threadIdx.x;
    int v = (i < N) ? counts[i] : 0;
#pragma unroll
    for (int d = 1; d < 64; d <<= 1) v += __shfl_xor(v, d);
    int wid = threadIdx.x >> 6;
    if ((threadIdx.x & 63) == 0) lds[wid] = v;
    __syncthreads();
    if (threadIdx.x == 0)
        tilesums[blockIdx.x] = lds[0] + lds[1] + lds[2] + lds[3];
    for (int w = i; w < 128 * 992; w += nthreads) {
        int j = w / 992, k = w % 992;
        int t = k >> 5, u = k & 31;
        float val = 0.f;
        if (j < 32) {
            if (t == 0) val = cg[0] * W[u * 32 + j];
            else if (t >= 7 && t < 16) {
                int r = t - 7, jy = r / 3, ii = r % 3;
                val = cg[19 + ii * 3 + jy] * W[3072 + u * 32 + j];
            }
        } else {
            int wch = (j - 32) / 3, m = (j - 32) % 3;
            if (t >= 1 && t <= 3) val = cg[1 + (t - 1) * 3 + m] * W[1024 + u * 32 + wch];
            else if (t >= 4 && t <= 6) val = cg[10 + (t - 4) * 3 + m] * W[2048 + u * 32 + wch];
            else if (t >= 16) {
                int r = t - 16, jy = r / 3, ii = r % 3;
                val = cg[28 + (ii * 5 + jy) * 3 + m] * W[4096 + u * 32 + wch];
            }
        }
        WBT[w] = bh(val);
    }
}

__global__ __launch_bounds__(256) void scanB_kernel(
    int* __restrict__ tilesums, int tiles) {
    __shared__ int lds[4];
    int tid = threadIdx.x;
    int v = (tid < tiles) ? tilesums[tid] : 0;
    int orig = v;
#pragma unroll
    for (int d = 1; d < 64; d <<= 1) {
        int t = __shfl_up(v, d);
        if ((tid & 63) >= d) v += t;
    }
    int wid = tid >> 6;
    if ((tid & 63) == 63) lds[wid] = v;
    __syncthreads();
    int base = 0;
    for (int q = 0; q < wid; ++q) base += lds[q];
    if (tid < tiles) tilesums[tid] = base + v - orig;  // exclusive
}

__global__ __launch_bounds__(256) void scanC_kernel(
    int* __restrict__ counts, const int* __restrict__ tilesums, int N) {
    __shared__ int lds[4];
    int i = blockIdx.x * 256 + threadIdx.x;
    int tid = threadIdx.x;
    int v = (i < N) ? counts[i] : 0;
    int orig = v;
#pragma unroll
    for (int d = 1; d < 64; d <<= 1) {
        int t = __shfl_up(v, d);
        if ((tid & 63) >= d) v += t;
    }
    int wid = tid >> 6;
    if ((tid & 63) == 63) lds[wid] = v;
    __syncthreads();
    int base = tilesums[blockIdx.x];
    for (int q = 0; q < wid; ++q) base += lds[q];
    if (i < N) counts[i] = base + v - orig;  // exclusive prefix
}

// ---------------------------------------------------------------------------
// scatter_ids: 4B id sort by dst (light scattered writes only)
// ---------------------------------------------------------------------------
__global__ __launch_bounds__(256) void scatter_ids_kernel(
    const int* __restrict__ eidx, int* __restrict__ cursor,
    int* __restrict__ eorder, int E) {
    int t = blockIdx.x * 256 + threadIdx.x;
    if (t >= E) return;
    int pos = atomicAdd(&cursor[eidx[E + t]], 1);
    eorder[pos] = t;
}
// After scatter_ids: cursor[d] == end of d's range.

// ---------------------------------------------------------------------------
// Per-edge accumulate: 31 raw outer-product FMAs, all indices compile-time.
// ---------------------------------------------------------------------------
__device__ inline void edge_accum31(const float* __restrict__ Y, uint2 f2,
                                    float g[31]) {
    float s = blo(f2.x), vx = bhi(f2.x);
    float vy = blo(f2.y), vz = bhi(f2.y);
    float v3[3] = {vx, vy, vz};
    g[0] = fmaf(Y[0], s, g[0]);
#pragma unroll
    for (int jy = 0; jy < 3; ++jy)
        g[1 + jy] = fmaf(Y[1 + jy], s, g[1 + jy]);
#pragma unroll
    for (int i = 0; i < 3; ++i)
        g[4 + i] = fmaf(Y[0], v3[i], g[4 + i]);
#pragma unroll
    for (int jy = 0; jy < 3; ++jy)
#pragma unroll
        for (int i = 0; i < 3; ++i)
            g[7 + jy * 3 + i] = fmaf(Y[1 + jy], v3[i], g[7 + jy * 3 + i]);
#pragma unroll
    for (int jy = 0; jy < 5; ++jy)
#pragma unroll
        for (int i = 0; i < 3; ++i)
            g[16 + jy * 3 + i] = fmaf(Y[4 + jy], v3[i], g[16 + jy * 3 + i]);
}

// ---------------------------------------------------------------------------
// Fused gather + MFMA: one 256-thread block per 16-dst tile. Phase 1: wave wv
// gathers dsts base+wv*4..+3 (lane u=lane&31, halves alternate edges, 2-edge
// unroll), reading sh DIRECTLY (random 36B, read-once) and fb rows; 31
// accumulators; shfl_xor(32) combine -> bf16 LDS Gs[16][1000].
// Phase 2: per wave 2 j-tiles, 31 K-steps of mfma_f32_16x16x32_bf16 vs WBT;
// A-frag read once per kk, shared across both j-tiles.
// D layout: lane l reg i -> out[base+(l>>4)*4+i][jt*16+(l&15)]  (verified).
// ---------------------------------------------------------------------------
__global__ __launch_bounds__(256) void gather_mfma_kernel(
    const unsigned* __restrict__ fb, const float* __restrict__ sh,
    const int* __restrict__ eidx, const int* __restrict__ eorder,
    const int* __restrict__ cursor, const unsigned short* __restrict__ WBT,
    float* __restrict__ out, int N) {
    __shared__ unsigned short Gs[16][1000];   // 2000B row stride, 16B-aligned
    int wv = threadIdx.x >> 6;
    int lane = threadIdx.x & 63;
    int half = lane >> 5, u = lane & 31;
    int base = blockIdx.x << 4;
    const uint2* fb2 = (const uint2*)fb;

#pragma unroll 1
    for (int d = 0; d < 4; ++d) {
        int row = wv * 4 + d;
        int node = base + row;
        if (node >= N) break;
        int start = node ? cursor[node - 1] : 0;
        int end = cursor[node];

        float g[31];
#pragma unroll
        for (int k = 0; k < 31; ++k) g[k] = 0.f;

        int idx = start + half;
        for (; idx + 2 < end; idx += 4) {  // 2-edge unroll: idx, idx+2
            int eA = eorder[idx];
            int eB = eorder[idx + 2];
            int srcA = eidx[eA];
            int srcB = eidx[eB];
            const float* YA = sh + (size_t)eA * 9;
            const float* YB = sh + (size_t)eB * 9;
            float ya[9], yb[9];
#pragma unroll
            for (int q = 0; q < 9; ++q) ya[q] = YA[q];
#pragma unroll
            for (int q = 0; q < 9; ++q) yb[q] = YB[q];
            uint2 fA = fb2[(size_t)srcA * 32 + u];
            uint2 fB = fb2[(size_t)srcB * 32 + u];
            edge_accum31(ya, fA, g);
            edge_accum31(yb, fB, g);
        }
        if (idx < end) {
            int e = eorder[idx];
            int src = eidx[e];
            const float* Ye = sh + (size_t)e * 9;
            float y[9];
#pragma unroll
            for (int q = 0; q < 9; ++q) y[q] = Ye[q];
            uint2 f2 = fb2[(size_t)src * 32 + u];
            edge_accum31(y, f2, g);
        }
#pragma unroll
        for (int k = 0; k < 31; ++k) g[k] += __shfl_xor(g[k], 32);
        if (half == 0) {
            unsigned short* Gr = &Gs[row][u];
#pragma unroll
            for (int k = 0; k < 31; ++k) Gr[k * 32] = bh(g[k]);
        }
    }
    __syncthreads();

    int r = lane & 15, q = lane >> 4;
    int jt0 = wv * 2, jt1 = wv * 2 + 1;
    f32x4 acc0 = {0.f, 0.f, 0.f, 0.f};
    f32x4 acc1 = {0.f, 0.f, 0.f, 0.f};
#pragma unroll
    for (int kk = 0; kk < 31; ++kk) {
        bf16x8 a = *(const bf16x8*)(&Gs[r][kk * 32 + q * 8]);
        bf16x8 b0 = *(const bf16x8*)(WBT + (size_t)(jt0 * 16 + r) * 992 + kk * 32 + q * 8);
        bf16x8 b1 = *(const bf16x8*)(WBT + (size_t)(jt1 * 16 + r) * 992 + kk * 32 + q * 8);
        acc0 = __builtin_amdgcn_mfma_f32_16x16x32_bf16(a, b0, acc0, 0, 0, 0);
        acc1 = __builtin_amdgcn_mfma_f32_16x16x32_bf16(a, b1, acc1, 0, 0, 0);
    }
#pragma unroll
    for (int i = 0; i < 4; ++i) {
        int n = base + q * 4 + i;
        if (n < N) {
            out[(size_t)n * 128 + jt0 * 16 + r] = acc0[i];
            out[(size_t)n * 128 + jt1 * 16 + r] = acc1[i];
        }
    }
}

extern "C" void kernel_launch(void* const* d_in, const int* in_sizes, int n_in,
                              void* d_out, int out_size, void* d_ws, size_t ws_size,
                              hipStream_t stream) {
    const float* feat = (const float*)d_in[0];
    const float* sh = (const float*)d_in[1];
    const int* eidx = (const int*)d_in[2];
    const float* W = (const float*)d_in[3];
    float* out = (float*)d_out;
    int N = in_sizes[0] / 128;
    int E = in_sizes[1] / 9;

    float* wsf = (float*)d_ws;
    float* cg = wsf;                                       // 128 words
    int* cursor = (int*)(wsf + 128);                       // N words
    int* eorder = cursor + N;                              // E words
    unsigned* fb = (unsigned*)(eorder + E);                // 64N words
    unsigned short* WBT = (unsigned short*)(fb + (size_t)64 * N);  // 126976 ushorts
    int* tilesums = (int*)(WBT + 128 * 992);               // 256 words (FIXED)

    int tiles = (N + 255) / 256;
    int ntiles16 = (N + 15) / 16;

    hipMemsetAsync(cursor, 0, (size_t)N * sizeof(int), stream);
    prep_kernel<<<(N * 32 + 255) / 256, 256, 0, stream>>>(feat, eidx, cursor, fb, cg, N, E);
    scanA_kernel<<<tiles, 256, 0, stream>>>(cursor, tilesums, N, W, cg, WBT, tiles * 256);
    scanB_kernel<<<1, 256, 0, stream>>>(tilesums, tiles);
    scanC_kernel<<<tiles, 256, 0, stream>>>(cursor, tilesums, N);
    scatter_ids_kernel<<<(E + 255) / 256, 256, 0, stream>>>(eidx, cursor, eorder, E);
    gather_mfma_kernel<<<ntiles16, 256, 0, stream>>>(fb, sh, eidx, eorder, cursor, WBT, out, N);
}

// Round 16
// 193.625 us; speedup vs baseline: 1.2787x; 1.2787x over previous
//
#include <hip/hip_runtime.h>
#include <math.h>

// ---------------------------------------------------------------------------
// u-space aggregation + fused MFMA epilogue (R13 structure, f32 Z-records).
//   gather:  G[n][t][u] = Sum_{e->n} z_t(Y_e) (x) feat_u[src_e]  (LDS, bf16)
//   fused:   out[n][j]  = Sum_k G[n][k] * WBT[j][k]  (16x16x32 bf16 MFMA)
// Workspace (4B words):
//   cg      [0..128)        CG tensors (alpha/norm folded)
//   cursor  [128 .. +N)     memset0 -> hist -> prefix -> cursor -> row ends
//   zrec    [64B-align .. +16E)  dst-sorted 64B f32 records (16 floats, NO
//                           bf16 packing -> no unpack VALU in gather):
//       f0={Y0,Z1_0,Z1_1,Z1_2} f1={Z3_0,Z3_1,Z3_2,Z4_00}
//       f2={Z4_01,Z4_02,Z4_10,Z4_11} f3={Z4_12,Z4_20,Z4_21,Z4_22}
//   srcs    [.. +E)         src id per dst-sorted position (seq read)
//   fb      [.. +64N)       feat bf16 [N][32] uint2 {P(s,vx),P(vy,vz)}
//   WBT     [.. +45056 ushorts) [128][352] (W bf16, cg0/c2 folded)
//   tilesums[.. +256)       per-tile sums for hierarchical scan
// ---------------------------------------------------------------------------

typedef __attribute__((ext_vector_type(8))) short bf16x8;
typedef __attribute__((ext_vector_type(4))) float f32x4;

__device__ inline float blo(unsigned u) { return __uint_as_float(u << 16); }
__device__ inline float bhi(unsigned u) { return __uint_as_float(u & 0xffff0000u); }
__device__ inline unsigned bpack(float a, float b) {
    unsigned ua = __float_as_uint(a);
    ua = (ua + 0x7fffu + ((ua >> 16) & 1u)) >> 16;
    unsigned ub = __float_as_uint(b);
    ub = (ub + 0x7fffu + ((ub >> 16) & 1u)) & 0xffff0000u;
    return ua | ub;
}
__device__ inline unsigned short bh(float a) {
    unsigned ua = __float_as_uint(a);
    return (unsigned short)((ua + 0x7fffu + ((ua >> 16) & 1u)) >> 16);
}

// f32 factorial (all n <= 7 here; exact in f32). Register-only scalar loop.
__device__ inline float dfactf(int n) {
    float r = 1.0f;
    for (int i = 2; i <= n; ++i) r *= (float)i;
    return r;
}

// SU(2) "CG" element via the reference's exact Racah-form (all six m-dependent
// factorials in the NUMERATOR — non-standard but matches the reference).
__device__ float su2_cg_elem_f(int l1, int l2, int l3, int i, int k, int n) {
    int m1 = i - l1, m2 = k - l2, m3 = n - l3;
    if (m1 + m2 != m3) return 0.0f;
    int vmin = -l1 + l2 + m3;
    if (-l1 + m1 > vmin) vmin = -l1 + m1;
    if (0 > vmin) vmin = 0;
    int vmax = l2 + l3 + m1;
    if (l3 - l1 + l2 < vmax) vmax = l3 - l1 + l2;
    if (l3 + m3 < vmax) vmax = l3 + m3;
    if (vmax < vmin) return 0.0f;
    float c = sqrtf((float)(2 * l3 + 1) * dfactf(l3 + l1 - l2) *
                    dfactf(l3 - l1 + l2) * dfactf(l1 + l2 - l3) /
                    dfactf(l1 + l2 + l3 + 1));
    c *= sqrtf(dfactf(l3 + m3) * dfactf(l3 - m3) * dfactf(l1 - m1) *
               dfactf(l1 + m1) * dfactf(l2 - m2) * dfactf(l2 + m2));
    float s = 0.0f;
    for (int v = vmin; v <= vmax; ++v) {
        float term = dfactf(l2 + l3 + m1 - v) * dfactf(l1 - m1 + v) /
                     (dfactf(v) * dfactf(l3 - l1 + l2 - v) *
                      dfactf(l3 + m3 - v) * dfactf(v + l1 - l2 - m3));
        if ((v + l2 + m2) & 1) term = -term;
        s += term;
    }
    return c * s;
}

// cg compute by one 256-thread block. All dynamically-indexed arrays in LDS
// (runtime-indexed private arrays go to SCRATCH -> 110us straggler, rule #20).
__device__ void cg_compute_block(float* __restrict__ cg_out) {
    __shared__ float sqr[3][5][5], sqi[3][5][5];  // q matrices for l=0,1,2
    __shared__ float vals[5][45];
    int t = threadIdx.x;
    if (t < 75) {
        int l = t / 25, a = (t % 25) / 5, b = t % 5;
        float re = 0.f, im = 0.f;
        const float inv = 0.70710678118654752440f;
        int m = a - l;
        if (a < 5 && b < 5) {
            if (m < 0) {
                if (b == l - m) re = inv;        // col l+|m|
                if (b == l + m) im = -inv;       // col l-|m|
            } else if (m == 0) {
                if (b == l && a == l) re = 1.f;
            } else {
                float sgn = (m & 1) ? -1.f : 1.f;
                if (b == l + m) re = sgn * inv;
                if (b == l - m) im = sgn * inv;
            }
        }
        if (l == 1) { float r = re; re = im; im = -r; }      // * (-i)
        else if (l == 2) { re = -re; im = -im; }             // * (-1)
        sqr[l][a][b] = re;
        sqi[l][a][b] = im;
    }
    __syncthreads();
    const int l1s[5] = {0, 0, 1, 1, 1};
    const int l2s[5] = {0, 1, 0, 1, 2};
    const int l3s[5] = {0, 1, 1, 0, 1};
    const int offs[5] = {0, 1, 10, 19, 28};
    const float alphas[5] = {0.125f, 0.10206207261596575f, 0.10206207261596575f,
                             0.125f, 0.10206207261596575f};
    int p = t / 45, idx = t % 45;
    bool active = (t < 225);
    float acc = 0.0f;
    int d1 = 0, d2 = 0, d3 = 0;
    if (active) {
        int l1 = l1s[p], l2 = l2s[p], l3 = l3s[p];
        d1 = 2 * l1 + 1; d2 = 2 * l2 + 1; d3 = 2 * l3 + 1;
        if (idx < d1 * d2 * d3) {
            int j = idx / (d2 * d3);
            int rem = idx % (d2 * d3);
            int l_ = rem / d3, m = rem % d3;
            for (int i = 0; i < d1; ++i)
                for (int k = 0; k < d2; ++k)
                    for (int n = 0; n < d3; ++n) {
                        float C = su2_cg_elem_f(l1, l2, l3, i, k, n);
                        if (C == 0.0f) continue;
                        float ar = sqr[l1][i][j], ai = sqi[l1][i][j];
                        float br = sqr[l2][k][l_], bi = sqi[l2][k][l_];
                        float cr = sqr[l3][n][m], ci = sqi[l3][n][m];
                        float abr = ar * br - ai * bi;
                        float abi = ar * bi + ai * br;
                        acc += (abr * cr + abi * ci) * C;  // Re(a*b*conj(c))
                    }
        }
        vals[p][idx] = acc;
    }
    __syncthreads();
    if (active && idx < d1 * d2 * d3) {
        float n2 = 0.0f;
        for (int q = 0; q < 45; ++q) n2 += vals[p][q] * vals[p][q];
        cg_out[offs[p] + idx] = acc * alphas[p] / sqrtf(n2);
    }
}

// ---------------------------------------------------------------------------
// prep: cg (block 0, LDS-based) + feat->bf16 transcode + dst histogram
// ---------------------------------------------------------------------------
__global__ __launch_bounds__(256) void prep_kernel(
    const float* __restrict__ feat, const int* __restrict__ eidx,
    int* __restrict__ cursor, unsigned* __restrict__ fb,
    float* __restrict__ cg, int N, int E) {
    if (blockIdx.x == 0) cg_compute_block(cg);
    int t = blockIdx.x * 256 + threadIdx.x;
    if (t < N * 32) {
        int n = t >> 5, u = t & 31;
        const float* f = feat + (size_t)n * 128;
        float s = f[u];
        float vx = f[32 + 3 * u], vy = f[33 + 3 * u], vz = f[34 + 3 * u];
        ((uint2*)fb)[t] = make_uint2(bpack(s, vx), bpack(vy, vz));
    }
    if (t < E) atomicAdd(&cursor[eidx[E + t]], 1);
}

// ---------------------------------------------------------------------------
// scanA (fused with WBT build)
// WBT[j][k], k = t*32+u:  j<32 (out0): t0 -> cg0*w0, t1 -> w3
//   j>=32: w=(j-32)/3, m=(j-32)%3: t2+mm -> (mm==m)*w1 ;
//   t5+i -> c2[i][m]*w2 ; t8+mm -> (mm==m)*w4
// ---------------------------------------------------------------------------
__global__ __launch_bounds__(256) void scanA_kernel(
    const int* __restrict__ counts, int* __restrict__ tilesums, int N,
    const float* __restrict__ W, const float* __restrict__ cg,
    unsigned short* __restrict__ WBT) {
    __shared__ int lds[4];
    int i = blockIdx.x * 256 + threadIdx.x;
    int v = (i < N) ? counts[i] : 0;
#pragma unroll
    for (int d = 1; d < 64; d <<= 1) v += __shfl_xor(v, d);
    int wid = threadIdx.x >> 6;
    if ((threadIdx.x & 63) == 0) lds[wid] = v;
    __syncthreads();
    if (threadIdx.x == 0)
        tilesums[blockIdx.x] = lds[0] + lds[1] + lds[2] + lds[3];
    int idx = i;
    if (idx < 128 * 352) {
        int j = idx / 352, k = idx % 352;
        int t = k >> 5, u = k & 31;
        float val = 0.f;
        if (j < 32) {
            if (t == 0) val = cg[0] * W[u * 32 + j];
            else if (t == 1) val = W[3072 + u * 32 + j];
        } else {
            int w = (j - 32) / 3, m = (j - 32) % 3;
            if (t >= 2 && t <= 4) { if (t - 2 == m) val = W[1024 + u * 32 + w]; }
            else if (t >= 5 && t <= 7) { val = cg[10 + (t - 5) * 3 + m] * W[2048 + u * 32 + w]; }
            else if (t >= 8) { if (t - 8 == m) val = W[4096 + u * 32 + w]; }
        }
        WBT[idx] = bh(val);
    }
}

__global__ __launch_bounds__(256) void scanB_kernel(
    int* __restrict__ tilesums, int tiles) {
    __shared__ int lds[4];
    int tid = threadIdx.x;
    int v = (tid < tiles) ? tilesums[tid] : 0;
    int orig = v;
#pragma unroll
    for (int d = 1; d < 64; d <<= 1) {
        int t = __shfl_up(v, d);
        if ((tid & 63) >= d) v += t;
    }
    int wid = tid >> 6;
    if ((tid & 63) == 63) lds[wid] = v;
    __syncthreads();
    int base = 0;
    for (int q = 0; q < wid; ++q) base += lds[q];
    if (tid < tiles) tilesums[tid] = base + v - orig;  // exclusive
}

__global__ __launch_bounds__(256) void scanC_kernel(
    int* __restrict__ counts, const int* __restrict__ tilesums, int N) {
    __shared__ int lds[4];
    int i = blockIdx.x * 256 + threadIdx.x;
    int tid = threadIdx.x;
    int v = (i < N) ? counts[i] : 0;
    int orig = v;
#pragma unroll
    for (int d = 1; d < 64; d <<= 1) {
        int t = __shfl_up(v, d);
        if ((tid & 63) >= d) v += t;
    }
    int wid = tid >> 6;
    if ((tid & 63) == 63) lds[wid] = v;
    __syncthreads();
    int base = tilesums[blockIdx.x];
    for (int q = 0; q < wid; ++q) base += lds[q];
    if (i < N) counts[i] = base + v - orig;  // exclusive prefix
}

// ---------------------------------------------------------------------------
// zscatter: per edge compute 16 lane-invariant Z values (CG (x) Y folded),
// write one 64B-aligned FULL-LINE f32 record (4x dwordx4, no RMW) at the
// dst-sorted position, plus src id into a parallel array.
// ---------------------------------------------------------------------------
__global__ __launch_bounds__(256) void zscatter_kernel(
    const int* __restrict__ eidx, const float* __restrict__ sh,
    const float* __restrict__ cg, int* __restrict__ cursor,
    float* __restrict__ zrec, int* __restrict__ srcs, int E) {
    int t = blockIdx.x * 256 + threadIdx.x;
    if (t >= E) return;
    int src = eidx[t];
    int dst = eidx[E + t];
    int pos = atomicAdd(&cursor[dst], 1);
    const float* Ye = sh + (size_t)t * 9;
    float Y0 = Ye[0];
    float Y1v[3] = {Ye[1], Ye[2], Ye[3]};
    float Y2v[5] = {Ye[4], Ye[5], Ye[6], Ye[7], Ye[8]};
    float Z1[3], Z3[3], Z4[9];
#pragma unroll
    for (int m = 0; m < 3; ++m)
        Z1[m] = fmaf(Y1v[0], cg[1 + m],
                fmaf(Y1v[1], cg[4 + m], Y1v[2] * cg[7 + m]));
#pragma unroll
    for (int i = 0; i < 3; ++i)
        Z3[i] = fmaf(Y1v[0], cg[19 + i * 3],
                fmaf(Y1v[1], cg[19 + i * 3 + 1], Y1v[2] * cg[19 + i * 3 + 2]));
#pragma unroll
    for (int i = 0; i < 3; ++i)
#pragma unroll
        for (int m = 0; m < 3; ++m) {
            float acc = 0.f;
#pragma unroll
            for (int j = 0; j < 5; ++j)
                acc = fmaf(Y2v[j], cg[28 + (i * 5 + j) * 3 + m], acc);
            Z4[i * 3 + m] = acc;
        }
    float4* rec = (float4*)(zrec + (size_t)pos * 16);
    rec[0] = make_float4(Y0, Z1[0], Z1[1], Z1[2]);
    rec[1] = make_float4(Z3[0], Z3[1], Z3[2], Z4[0]);
    rec[2] = make_float4(Z4[1], Z4[2], Z4[3], Z4[4]);
    rec[3] = make_float4(Z4[5], Z4[6], Z4[7], Z4[8]);
    srcs[pos] = src;
}
// After zscatter: cursor[d] == end of d's range.

// ---------------------------------------------------------------------------
// Per-edge accumulate (f32 record — zero unpack ops; only fb needs 4).
// ---------------------------------------------------------------------------
__device__ inline void edge_accum(
    float4 r0, float4 r1, float4 r2, float4 r3, uint2 f2,
    float& g0, float& g1, float& g2, float& g3, float& g4, float& g5,
    float& g6, float& g7, float& g8, float& g9, float& g10) {
    float sF = blo(f2.x), vx = bhi(f2.x);
    float vy = blo(f2.y), vz = bhi(f2.y);
    float y0 = r0.x, z10 = r0.y, z11 = r0.z, z12 = r0.w;
    float z30 = r1.x, z31 = r1.y, z32 = r1.z, z400 = r1.w;
    float z401 = r2.x, z402 = r2.y, z410 = r2.z, z411 = r2.w;
    float z412 = r3.x, z420 = r3.y, z421 = r3.z, z422 = r3.w;
    g0 = fmaf(y0, sF, g0);                                          // t0
    g1 = fmaf(z30, vx, fmaf(z31, vy, fmaf(z32, vz, g1)));           // t1
    g2 = fmaf(z10, sF, g2);  g3 = fmaf(z11, sF, g3);  g4 = fmaf(z12, sF, g4);
    g5 = fmaf(y0, vx, g5);   g6 = fmaf(y0, vy, g6);   g7 = fmaf(y0, vz, g7);
    g8 = fmaf(vx, z400, fmaf(vy, z410, fmaf(vz, z420, g8)));
    g9 = fmaf(vx, z401, fmaf(vy, z411, fmaf(vz, z421, g9)));
    g10 = fmaf(vx, z402, fmaf(vy, z412, fmaf(vz, z422, g10)));
}

// ---------------------------------------------------------------------------
// Fused gather + MFMA: one 256-thread block per 16-dst tile. Phase 1: wave wv
// gathers dsts base+wv*4..+3 (lane u=lane&31, halves alternate edges, 2-edge
// unroll, shfl_xor(32) combine) -> bf16 LDS Gs[16][360].
// Phase 2: each wave does 2 j-tiles of mfma_f32_16x16x32_bf16 vs WBT.
// D layout: lane l reg i -> out[base+(l>>4)*4+i][jt*16+(l&15)]  (verified).
// ---------------------------------------------------------------------------
__global__ __launch_bounds__(256) void gather_mfma_kernel(
    const unsigned* __restrict__ fb, const float* __restrict__ zrec,
    const int* __restrict__ srcs, const int* __restrict__ cursor,
    const unsigned short* __restrict__ WBT, float* __restrict__ out, int N) {
    __shared__ unsigned short Gs[16][360];
    int wv = threadIdx.x >> 6;
    int lane = threadIdx.x & 63;
    int half = lane >> 5, u = lane & 31;
    int base = blockIdx.x << 4;
    const uint2* fb2 = (const uint2*)fb;

#pragma unroll 1
    for (int d = 0; d < 4; ++d) {
        int row = wv * 4 + d;
        int node = base + row;
        if (node >= N) break;
        int start = node ? cursor[node - 1] : 0;
        int end = cursor[node];

        float g0 = 0.f, g1 = 0.f, g2 = 0.f, g3 = 0.f, g4 = 0.f, g5 = 0.f;
        float g6 = 0.f, g7 = 0.f, g8 = 0.f, g9 = 0.f, g10 = 0.f;

        int idx = start + half;
        for (; idx + 2 < end; idx += 4) {  // 2-edge unroll: idx, idx+2
            const float4* rA = (const float4*)(zrec + (size_t)idx * 16);
            const float4* rB = (const float4*)(zrec + (size_t)(idx + 2) * 16);
            int srcA = srcs[idx];
            int srcB = srcs[idx + 2];
            float4 a0 = rA[0], a1 = rA[1], a2 = rA[2], a3 = rA[3];
            float4 b0 = rB[0], b1 = rB[1], b2 = rB[2], b3 = rB[3];
            uint2 fA = fb2[(size_t)srcA * 32 + u];
            uint2 fB = fb2[(size_t)srcB * 32 + u];
            edge_accum(a0, a1, a2, a3, fA, g0, g1, g2, g3, g4, g5, g6, g7, g8, g9, g10);
            edge_accum(b0, b1, b2, b3, fB, g0, g1, g2, g3, g4, g5, g6, g7, g8, g9, g10);
        }
        if (idx < end) {
            const float4* r = (const float4*)(zrec + (size_t)idx * 16);
            int src = srcs[idx];
            float4 q0 = r[0], q1 = r[1], q2 = r[2], q3 = r[3];
            uint2 f2 = fb2[(size_t)src * 32 + u];
            edge_accum(q0, q1, q2, q3, f2, g0, g1, g2, g3, g4, g5, g6, g7, g8, g9, g10);
        }
        g0 += __shfl_xor(g0, 32);  g1 += __shfl_xor(g1, 32);
        g2 += __shfl_xor(g2, 32);  g3 += __shfl_xor(g3, 32);
        g4 += __shfl_xor(g4, 32);  g5 += __shfl_xor(g5, 32);
        g6 += __shfl_xor(g6, 32);  g7 += __shfl_xor(g7, 32);
        g8 += __shfl_xor(g8, 32);  g9 += __shfl_xor(g9, 32);
        g10 += __shfl_xor(g10, 32);

        if (half == 0) {
            unsigned short* Gr = &Gs[row][u];
            Gr[0] = bh(g0);        // t=0
            Gr[32] = bh(g1);       // t=1
            Gr[64] = bh(g2);  Gr[96] = bh(g3);   Gr[128] = bh(g4);
            Gr[160] = bh(g5); Gr[192] = bh(g6);  Gr[224] = bh(g7);
            Gr[256] = bh(g8); Gr[288] = bh(g9);  Gr[320] = bh(g10);
        }
    }
    __syncthreads();

    int r = lane & 15, q = lane >> 4;
    bf16x8 a[11];
#pragma unroll
    for (int kk = 0; kk < 11; ++kk)
        a[kk] = *(const bf16x8*)(&Gs[r][kk * 32 + q * 8]);

#pragma unroll
    for (int jj = 0; jj < 2; ++jj) {
        int jt = wv * 2 + jj;
        f32x4 acc = {0.f, 0.f, 0.f, 0.f};
#pragma unroll
        for (int kk = 0; kk < 11; ++kk) {
            bf16x8 b = *(const bf16x8*)(WBT + (size_t)(jt * 16 + r) * 352 + kk * 32 + q * 8);
            acc = __builtin_amdgcn_mfma_f32_16x16x32_bf16(a[kk], b, acc, 0, 0, 0);
        }
#pragma unroll
        for (int i = 0; i < 4; ++i) {
            int n = base + q * 4 + i;
            if (n < N) out[(size_t)n * 128 + jt * 16 + r] = acc[i];
        }
    }
}

extern "C" void kernel_launch(void* const* d_in, const int* in_sizes, int n_in,
                              void* d_out, int out_size, void* d_ws, size_t ws_size,
                              hipStream_t stream) {
    const float* feat = (const float*)d_in[0];
    const float* sh = (const float*)d_in[1];
    const int* eidx = (const int*)d_in[2];
    const float* W = (const float*)d_in[3];
    float* out = (float*)d_out;
    int N = in_sizes[0] / 128;
    int E = in_sizes[1] / 9;

    float* wsf = (float*)d_ws;
    float* cg = wsf;                                       // 128 words
    int* cursor = (int*)(wsf + 128);                       // N words
    size_t off = (size_t)(128 + N + 15) & ~(size_t)15;     // 64B align
    float* zrec = wsf + off;                               // 16E words (f32)
    int* srcs = (int*)(zrec + (size_t)16 * E);             // E words
    unsigned* fb = (unsigned*)(srcs + E);                  // 64N words
    unsigned short* WBT = (unsigned short*)(fb + (size_t)64 * N);  // 45056 ushorts
    int* tilesums = (int*)(WBT + 45056);                   // 256 words

    int tiles = (N + 255) / 256;
    int ntiles16 = (N + 15) / 16;

    hipMemsetAsync(cursor, 0, (size_t)N * sizeof(int), stream);
    prep_kernel<<<(N * 32 + 255) / 256, 256, 0, stream>>>(feat, eidx, cursor, fb, cg, N, E);
    scanA_kernel<<<tiles, 256, 0, stream>>>(cursor, tilesums, N, W, cg, WBT);
    scanB_kernel<<<1, 256, 0, stream>>>(tilesums, tiles);
    scanC_kernel<<<tiles, 256, 0, stream>>>(cursor, tilesums, N);
    zscatter_kernel<<<(E + 255) / 256, 256, 0, stream>>>(eidx, sh, cg, cursor, zrec, srcs, E);
    gather_mfma_kernel<<<ntiles16, 256, 0, stream>>>(fb, zrec, srcs, cursor, WBT, out, N);
}

// Round 17
// 180.552 us; speedup vs baseline: 1.3713x; 1.0724x over previous
//
#include <hip/hip_runtime.h>
#include <math.h>

// ---------------------------------------------------------------------------
// u-space aggregation + fused MFMA epilogue (R13 structure + separate srcs
// array to break gather's zrec->src->fb serial dependence).
//   gather:  G[n][t][u] = Sum_{e->n} z_t(Y_e) (x) feat_u[src_e]  (LDS, bf16)
//   fused:   out[n][j]  = Sum_k G[n][k] * WBT[j][k]  (16x16x32 bf16 MFMA)
// Workspace (4B words):
//   cg      [0..128)        CG tensors (alpha/norm folded)
//   cursor  [128 .. +N)     memset0 -> hist -> prefix -> cursor -> row ends
//   zrec    [64B-align .. +16E)  dst-sorted records, 64B stride (full-line
//       writes), payload 32B = 16 bf16 in 8 uints:
//       u0=P(Y0,Z1_0) u1=P(Z1_1,Z1_2) u2=P(Z3_0,Z3_1) u3=P(Z3_2,Z4_00)
//       u4=P(Z4_01,Z4_02) u5=P(Z4_10,Z4_11) u6=P(Z4_12,Z4_20) u7=P(Z4_21,Z4_22)
//   srcs    [.. +E)         src id per dst-sorted position (seq read in gather)
//   fb      [.. +64N)       feat bf16 [N][32] uint2 {P(s,vx),P(vy,vz)}
//   WBT     [.. +22528 words) ushort [128][352] (W bf16, cg0/c2 folded)
//   tilesums[.. +256)
// ---------------------------------------------------------------------------

typedef __attribute__((ext_vector_type(8))) short bf16x8;
typedef __attribute__((ext_vector_type(4))) float f32x4;

__device__ inline float blo(unsigned u) { return __uint_as_float(u << 16); }
__device__ inline float bhi(unsigned u) { return __uint_as_float(u & 0xffff0000u); }
__device__ inline unsigned bpack(float a, float b) {
    unsigned ua = __float_as_uint(a);
    ua = (ua + 0x7fffu + ((ua >> 16) & 1u)) >> 16;
    unsigned ub = __float_as_uint(b);
    ub = (ub + 0x7fffu + ((ub >> 16) & 1u)) & 0xffff0000u;
    return ua | ub;
}
__device__ inline unsigned short bh(float a) {
    unsigned ua = __float_as_uint(a);
    return (unsigned short)((ua + 0x7fffu + ((ua >> 16) & 1u)) >> 16);
}

// f32 factorial (all n <= 7 here; exact in f32). Register-only scalar loop.
__device__ inline float dfactf(int n) {
    float r = 1.0f;
    for (int i = 2; i <= n; ++i) r *= (float)i;
    return r;
}

// SU(2) "CG" element via the reference's exact Racah-form (all six m-dependent
// factorials in the NUMERATOR — non-standard but matches the reference).
__device__ float su2_cg_elem_f(int l1, int l2, int l3, int i, int k, int n) {
    int m1 = i - l1, m2 = k - l2, m3 = n - l3;
    if (m1 + m2 != m3) return 0.0f;
    int vmin = -l1 + l2 + m3;
    if (-l1 + m1 > vmin) vmin = -l1 + m1;
    if (0 > vmin) vmin = 0;
    int vmax = l2 + l3 + m1;
    if (l3 - l1 + l2 < vmax) vmax = l3 - l1 + l2;
    if (l3 + m3 < vmax) vmax = l3 + m3;
    if (vmax < vmin) return 0.0f;
    float c = sqrtf((float)(2 * l3 + 1) * dfactf(l3 + l1 - l2) *
                    dfactf(l3 - l1 + l2) * dfactf(l1 + l2 - l3) /
                    dfactf(l1 + l2 + l3 + 1));
    c *= sqrtf(dfactf(l3 + m3) * dfactf(l3 - m3) * dfactf(l1 - m1) *
               dfactf(l1 + m1) * dfactf(l2 - m2) * dfactf(l2 + m2));
    float s = 0.0f;
    for (int v = vmin; v <= vmax; ++v) {
        float term = dfactf(l2 + l3 + m1 - v) * dfactf(l1 - m1 + v) /
                     (dfactf(v) * dfactf(l3 - l1 + l2 - v) *
                      dfactf(l3 + m3 - v) * dfactf(v + l1 - l2 - m3));
        if ((v + l2 + m2) & 1) term = -term;
        s += term;
    }
    return c * s;
}

// cg compute by one 256-thread block. All dynamically-indexed arrays in LDS
// (runtime-indexed private arrays go to SCRATCH -> 110us straggler, rule #20).
__device__ void cg_compute_block(float* __restrict__ cg_out) {
    __shared__ float sqr[3][5][5], sqi[3][5][5];  // q matrices for l=0,1,2
    __shared__ float vals[5][45];
    int t = threadIdx.x;
    if (t < 75) {
        int l = t / 25, a = (t % 25) / 5, b = t % 5;
        float re = 0.f, im = 0.f;
        const float inv = 0.70710678118654752440f;
        int m = a - l;
        if (a < 5 && b < 5) {
            if (m < 0) {
                if (b == l - m) re = inv;        // col l+|m|
                if (b == l + m) im = -inv;       // col l-|m|
            } else if (m == 0) {
                if (b == l && a == l) re = 1.f;
            } else {
                float sgn = (m & 1) ? -1.f : 1.f;
                if (b == l + m) re = sgn * inv;
                if (b == l - m) im = sgn * inv;
            }
        }
        if (l == 1) { float r = re; re = im; im = -r; }      // * (-i)
        else if (l == 2) { re = -re; im = -im; }             // * (-1)
        sqr[l][a][b] = re;
        sqi[l][a][b] = im;
    }
    __syncthreads();
    const int l1s[5] = {0, 0, 1, 1, 1};
    const int l2s[5] = {0, 1, 0, 1, 2};
    const int l3s[5] = {0, 1, 1, 0, 1};
    const int offs[5] = {0, 1, 10, 19, 28};
    const float alphas[5] = {0.125f, 0.10206207261596575f, 0.10206207261596575f,
                             0.125f, 0.10206207261596575f};
    int p = t / 45, idx = t % 45;
    bool active = (t < 225);
    float acc = 0.0f;
    int d1 = 0, d2 = 0, d3 = 0;
    if (active) {
        int l1 = l1s[p], l2 = l2s[p], l3 = l3s[p];
        d1 = 2 * l1 + 1; d2 = 2 * l2 + 1; d3 = 2 * l3 + 1;
        if (idx < d1 * d2 * d3) {
            int j = idx / (d2 * d3);
            int rem = idx % (d2 * d3);
            int l_ = rem / d3, m = rem % d3;
            for (int i = 0; i < d1; ++i)
                for (int k = 0; k < d2; ++k)
                    for (int n = 0; n < d3; ++n) {
                        float C = su2_cg_elem_f(l1, l2, l3, i, k, n);
                        if (C == 0.0f) continue;
                        float ar = sqr[l1][i][j], ai = sqi[l1][i][j];
                        float br = sqr[l2][k][l_], bi = sqi[l2][k][l_];
                        float cr = sqr[l3][n][m], ci = sqi[l3][n][m];
                        float abr = ar * br - ai * bi;
                        float abi = ar * bi + ai * br;
                        acc += (abr * cr + abi * ci) * C;  // Re(a*b*conj(c))
                    }
        }
        vals[p][idx] = acc;
    }
    __syncthreads();
    if (active && idx < d1 * d2 * d3) {
        float n2 = 0.0f;
        for (int q = 0; q < 45; ++q) n2 += vals[p][q] * vals[p][q];
        cg_out[offs[p] + idx] = acc * alphas[p] / sqrtf(n2);
    }
}

// ---------------------------------------------------------------------------
// prep: cg (block 0, LDS-based) + feat->bf16 transcode + dst histogram
// ---------------------------------------------------------------------------
__global__ __launch_bounds__(256) void prep_kernel(
    const float* __restrict__ feat, const int* __restrict__ eidx,
    int* __restrict__ cursor, unsigned* __restrict__ fb,
    float* __restrict__ cg, int N, int E) {
    if (blockIdx.x == 0) cg_compute_block(cg);
    int t = blockIdx.x * 256 + threadIdx.x;
    if (t < N * 32) {
        int n = t >> 5, u = t & 31;
        const float* f = feat + (size_t)n * 128;
        float s = f[u];
        float vx = f[32 + 3 * u], vy = f[33 + 3 * u], vz = f[34 + 3 * u];
        ((uint2*)fb)[t] = make_uint2(bpack(s, vx), bpack(vy, vz));
    }
    if (t < E) atomicAdd(&cursor[eidx[E + t]], 1);
}

// ---------------------------------------------------------------------------
// scanA (fused with WBT build)
// WBT[j][k], k = t*32+u:  j<32 (out0): t0 -> cg0*w0, t1 -> w3
//   j>=32: w=(j-32)/3, m=(j-32)%3: t2+mm -> (mm==m)*w1 ;
//   t5+i -> c2[i][m]*w2 ; t8+mm -> (mm==m)*w4
// ---------------------------------------------------------------------------
__global__ __launch_bounds__(256) void scanA_kernel(
    const int* __restrict__ counts, int* __restrict__ tilesums, int N,
    const float* __restrict__ W, const float* __restrict__ cg,
    unsigned short* __restrict__ WBT) {
    __shared__ int lds[4];
    int i = blockIdx.x * 256 + threadIdx.x;
    int v = (i < N) ? counts[i] : 0;
#pragma unroll
    for (int d = 1; d < 64; d <<= 1) v += __shfl_xor(v, d);
    int wid = threadIdx.x >> 6;
    if ((threadIdx.x & 63) == 0) lds[wid] = v;
    __syncthreads();
    if (threadIdx.x == 0)
        tilesums[blockIdx.x] = lds[0] + lds[1] + lds[2] + lds[3];
    int idx = i;
    if (idx < 128 * 352) {
        int j = idx / 352, k = idx % 352;
        int t = k >> 5, u = k & 31;
        float val = 0.f;
        if (j < 32) {
            if (t == 0) val = cg[0] * W[u * 32 + j];
            else if (t == 1) val = W[3072 + u * 32 + j];
        } else {
            int w = (j - 32) / 3, m = (j - 32) % 3;
            if (t >= 2 && t <= 4) { if (t - 2 == m) val = W[1024 + u * 32 + w]; }
            else if (t >= 5 && t <= 7) { val = cg[10 + (t - 5) * 3 + m] * W[2048 + u * 32 + w]; }
            else if (t >= 8) { if (t - 8 == m) val = W[4096 + u * 32 + w]; }
        }
        WBT[idx] = bh(val);
    }
}

__global__ __launch_bounds__(256) void scanB_kernel(
    int* __restrict__ tilesums, int tiles) {
    __shared__ int lds[4];
    int tid = threadIdx.x;
    int v = (tid < tiles) ? tilesums[tid] : 0;
    int orig = v;
#pragma unroll
    for (int d = 1; d < 64; d <<= 1) {
        int t = __shfl_up(v, d);
        if ((tid & 63) >= d) v += t;
    }
    int wid = tid >> 6;
    if ((tid & 63) == 63) lds[wid] = v;
    __syncthreads();
    int base = 0;
    for (int q = 0; q < wid; ++q) base += lds[q];
    if (tid < tiles) tilesums[tid] = base + v - orig;  // exclusive
}

__global__ __launch_bounds__(256) void scanC_kernel(
    int* __restrict__ counts, const int* __restrict__ tilesums, int N) {
    __shared__ int lds[4];
    int i = blockIdx.x * 256 + threadIdx.x;
    int tid = threadIdx.x;
    int v = (i < N) ? counts[i] : 0;
    int orig = v;
#pragma unroll
    for (int d = 1; d < 64; d <<= 1) {
        int t = __shfl_up(v, d);
        if ((tid & 63) >= d) v += t;
    }
    int wid = tid >> 6;
    if ((tid & 63) == 63) lds[wid] = v;
    __syncthreads();
    int base = tilesums[blockIdx.x];
    for (int q = 0; q < wid; ++q) base += lds[q];
    if (i < N) counts[i] = base + v - orig;  // exclusive prefix
}

// ---------------------------------------------------------------------------
// zscatter: per edge compute 16 lane-invariant Z values (CG (x) Y folded),
// write one 64B-aligned FULL-LINE record (32B payload + 32B pad, 4x dwordx4
// back-to-back -> write-combine, no RMW) + src id to parallel array.
// ---------------------------------------------------------------------------
__global__ __launch_bounds__(256) void zscatter_kernel(
    const int* __restrict__ eidx, const float* __restrict__ sh,
    const float* __restrict__ cg, int* __restrict__ cursor,
    unsigned* __restrict__ zrec, int* __restrict__ srcs, int E) {
    int t = blockIdx.x * 256 + threadIdx.x;
    if (t >= E) return;
    int src = eidx[t];
    int dst = eidx[E + t];
    int pos = atomicAdd(&cursor[dst], 1);
    const float* Ye = sh + (size_t)t * 9;
    float Y0 = Ye[0];
    float Y1v[3] = {Ye[1], Ye[2], Ye[3]};
    float Y2v[5] = {Ye[4], Ye[5], Ye[6], Ye[7], Ye[8]};
    float Z1[3], Z3[3], Z4[9];
#pragma unroll
    for (int m = 0; m < 3; ++m)
        Z1[m] = fmaf(Y1v[0], cg[1 + m],
                fmaf(Y1v[1], cg[4 + m], Y1v[2] * cg[7 + m]));
#pragma unroll
    for (int i = 0; i < 3; ++i)
        Z3[i] = fmaf(Y1v[0], cg[19 + i * 3],
                fmaf(Y1v[1], cg[19 + i * 3 + 1], Y1v[2] * cg[19 + i * 3 + 2]));
#pragma unroll
    for (int i = 0; i < 3; ++i)
#pragma unroll
        for (int m = 0; m < 3; ++m) {
            float acc = 0.f;
#pragma unroll
            for (int j = 0; j < 5; ++j)
                acc = fmaf(Y2v[j], cg[28 + (i * 5 + j) * 3 + m], acc);
            Z4[i * 3 + m] = acc;
        }
    uint4* rec = (uint4*)(zrec + (size_t)pos * 16);
    rec[0] = make_uint4(bpack(Y0, Z1[0]), bpack(Z1[1], Z1[2]),
                        bpack(Z3[0], Z3[1]), bpack(Z3[2], Z4[0]));
    rec[1] = make_uint4(bpack(Z4[1], Z4[2]), bpack(Z4[3], Z4[4]),
                        bpack(Z4[5], Z4[6]), bpack(Z4[7], Z4[8]));
    rec[2] = make_uint4(0u, 0u, 0u, 0u);
    rec[3] = make_uint4(0u, 0u, 0u, 0u);
    srcs[pos] = src;
}
// After zscatter: cursor[d] == end of d's range.

// ---------------------------------------------------------------------------
// Per-edge accumulate (32B bf16 record; src arrives separately).
// ---------------------------------------------------------------------------
__device__ inline void edge_accum(
    uint4 q0, uint4 q1, uint2 f2,
    float& g0, float& g1, float& g2, float& g3, float& g4, float& g5,
    float& g6, float& g7, float& g8, float& g9, float& g10) {
    float sF = blo(f2.x), vx = bhi(f2.x);
    float vy = blo(f2.y), vz = bhi(f2.y);
    float y0 = blo(q0.x), z10 = bhi(q0.x);
    float z11 = blo(q0.y), z12 = bhi(q0.y);
    float z30 = blo(q0.z), z31 = bhi(q0.z);
    float z32 = blo(q0.w), z400 = bhi(q0.w);
    float z401 = blo(q1.x), z402 = bhi(q1.x);
    float z410 = blo(q1.y), z411 = bhi(q1.y);
    float z412 = blo(q1.z), z420 = bhi(q1.z);
    float z421 = blo(q1.w), z422 = bhi(q1.w);
    g0 = fmaf(y0, sF, g0);                                          // t0
    g1 = fmaf(z30, vx, fmaf(z31, vy, fmaf(z32, vz, g1)));           // t1
    g2 = fmaf(z10, sF, g2);  g3 = fmaf(z11, sF, g3);  g4 = fmaf(z12, sF, g4);
    g5 = fmaf(y0, vx, g5);   g6 = fmaf(y0, vy, g6);   g7 = fmaf(y0, vz, g7);
    g8 = fmaf(vx, z400, fmaf(vy, z410, fmaf(vz, z420, g8)));
    g9 = fmaf(vx, z401, fmaf(vy, z411, fmaf(vz, z421, g9)));
    g10 = fmaf(vx, z402, fmaf(vy, z412, fmaf(vz, z422, g10)));
}

// ---------------------------------------------------------------------------
// Fused gather + MFMA: one 256-thread block per 16-dst tile. Phase 1: wave wv
// gathers dsts base+wv*4..+3 (lane u=lane&31, halves alternate edges, 2-edge
// unroll). KEY: srcs[] loaded FIRST (seq, cheap) so fb loads issue without
// waiting for the fat zrec loads -> fb and zrec latencies overlap.
// Phase 2: each wave does 2 j-tiles of mfma_f32_16x16x32_bf16 vs WBT.
// D layout: lane l reg i -> out[base+(l>>4)*4+i][jt*16+(l&15)]  (verified).
// ---------------------------------------------------------------------------
__global__ __launch_bounds__(256) void gather_mfma_kernel(
    const unsigned* __restrict__ fb, const unsigned* __restrict__ zrec,
    const int* __restrict__ srcs, const int* __restrict__ cursor,
    const unsigned short* __restrict__ WBT, float* __restrict__ out, int N) {
    __shared__ unsigned short Gs[16][360];
    int wv = threadIdx.x >> 6;
    int lane = threadIdx.x & 63;
    int half = lane >> 5, u = lane & 31;
    int base = blockIdx.x << 4;
    const uint2* fb2 = (const uint2*)fb;

#pragma unroll 1
    for (int d = 0; d < 4; ++d) {
        int row = wv * 4 + d;
        int node = base + row;
        if (node >= N) break;
        int start = node ? cursor[node - 1] : 0;
        int end = cursor[node];

        float g0 = 0.f, g1 = 0.f, g2 = 0.f, g3 = 0.f, g4 = 0.f, g5 = 0.f;
        float g6 = 0.f, g7 = 0.f, g8 = 0.f, g9 = 0.f, g10 = 0.f;

        int idx = start + half;
        for (; idx + 2 < end; idx += 4) {  // 2-edge unroll: idx, idx+2
            int srcA = srcs[idx];
            int srcB = srcs[idx + 2];
            uint2 fA = fb2[(size_t)srcA * 32 + u];
            uint2 fB = fb2[(size_t)srcB * 32 + u];
            const uint4* rA = (const uint4*)(zrec + (size_t)idx * 16);
            const uint4* rB = (const uint4*)(zrec + (size_t)(idx + 2) * 16);
            uint4 a0 = rA[0], a1 = rA[1];
            uint4 b0 = rB[0], b1 = rB[1];
            edge_accum(a0, a1, fA, g0, g1, g2, g3, g4, g5, g6, g7, g8, g9, g10);
            edge_accum(b0, b1, fB, g0, g1, g2, g3, g4, g5, g6, g7, g8, g9, g10);
        }
        if (idx < end) {
            int src = srcs[idx];
            uint2 f2 = fb2[(size_t)src * 32 + u];
            const uint4* r = (const uint4*)(zrec + (size_t)idx * 16);
            uint4 q0 = r[0], q1 = r[1];
            edge_accum(q0, q1, f2, g0, g1, g2, g3, g4, g5, g6, g7, g8, g9, g10);
        }
        g0 += __shfl_xor(g0, 32);  g1 += __shfl_xor(g1, 32);
        g2 += __shfl_xor(g2, 32);  g3 += __shfl_xor(g3, 32);
        g4 += __shfl_xor(g4, 32);  g5 += __shfl_xor(g5, 32);
        g6 += __shfl_xor(g6, 32);  g7 += __shfl_xor(g7, 32);
        g8 += __shfl_xor(g8, 32);  g9 += __shfl_xor(g9, 32);
        g10 += __shfl_xor(g10, 32);

        if (half == 0) {
            unsigned short* Gr = &Gs[row][u];
            Gr[0] = bh(g0);        // t=0
            Gr[32] = bh(g1);       // t=1
            Gr[64] = bh(g2);  Gr[96] = bh(g3);   Gr[128] = bh(g4);
            Gr[160] = bh(g5); Gr[192] = bh(g6);  Gr[224] = bh(g7);
            Gr[256] = bh(g8); Gr[288] = bh(g9);  Gr[320] = bh(g10);
        }
    }
    __syncthreads();

    int r = lane & 15, q = lane >> 4;
    bf16x8 a[11];
#pragma unroll
    for (int kk = 0; kk < 11; ++kk)
        a[kk] = *(const bf16x8*)(&Gs[r][kk * 32 + q * 8]);

#pragma unroll
    for (int jj = 0; jj < 2; ++jj) {
        int jt = wv * 2 + jj;
        f32x4 acc = {0.f, 0.f, 0.f, 0.f};
#pragma unroll
        for (int kk = 0; kk < 11; ++kk) {
            bf16x8 b = *(const bf16x8*)(WBT + (size_t)(jt * 16 + r) * 352 + kk * 32 + q * 8);
            acc = __builtin_amdgcn_mfma_f32_16x16x32_bf16(a[kk], b, acc, 0, 0, 0);
        }
#pragma unroll
        for (int i = 0; i < 4; ++i) {
            int n = base + q * 4 + i;
            if (n < N) out[(size_t)n * 128 + jt * 16 + r] = acc[i];
        }
    }
}

extern "C" void kernel_launch(void* const* d_in, const int* in_sizes, int n_in,
                              void* d_out, int out_size, void* d_ws, size_t ws_size,
                              hipStream_t stream) {
    const float* feat = (const float*)d_in[0];
    const float* sh = (const float*)d_in[1];
    const int* eidx = (const int*)d_in[2];
    const float* W = (const float*)d_in[3];
    float* out = (float*)d_out;
    int N = in_sizes[0] / 128;
    int E = in_sizes[1] / 9;

    float* wsf = (float*)d_ws;
    float* cg = wsf;                                       // 128 words
    int* cursor = (int*)(wsf + 128);                       // N words
    size_t off = (size_t)(128 + N + 15) & ~(size_t)15;     // 64B align
    unsigned* zrec = (unsigned*)(wsf + off);               // 16E words
    int* srcs = (int*)(zrec + (size_t)16 * E);             // E words
    unsigned* fb = (unsigned*)(srcs + E);                  // 64N words
    unsigned short* WBT = (unsigned short*)(fb + (size_t)64 * N);  // 45056 ushorts
    int* tilesums = (int*)(WBT + 45056);                   // 256 words

    int tiles = (N + 255) / 256;
    int ntiles16 = (N + 15) / 16;

    hipMemsetAsync(cursor, 0, (size_t)N * sizeof(int), stream);
    prep_kernel<<<(N * 32 + 255) / 256, 256, 0, stream>>>(feat, eidx, cursor, fb, cg, N, E);
    scanA_kernel<<<tiles, 256, 0, stream>>>(cursor, tilesums, N, W, cg, WBT);
    scanB_kernel<<<1, 256, 0, stream>>>(tilesums, tiles);
    scanC_kernel<<<tiles, 256, 0, stream>>>(cursor, tilesums, N);
    zscatter_kernel<<<(E + 255) / 256, 256, 0, stream>>>(eidx, sh, cg, cursor, zrec, srcs, E);
    gather_mfma_kernel<<<ntiles16, 256, 0, stream>>>(fb, zrec, srcs, cursor, WBT, out, N);
}